// Round 4
// baseline (1006.218 us; speedup 1.0000x reference)
//
#include <hip/hip_runtime.h>
#include <hip/hip_bf16.h>
#include <math.h>

typedef unsigned short u16;
typedef __attribute__((ext_vector_type(4))) unsigned short u16x4;
typedef __attribute__((ext_vector_type(8))) unsigned short u16x8;
typedef __attribute__((ext_vector_type(8))) short s16x8;
typedef __attribute__((ext_vector_type(4))) float f32x4;

#define B_  4
#define S_  2048
#define D_  2048
#define DI_ 1024
#define MROWS (B_ * S_)          // 8192
#define KDIM  D_                 // 2048
#define NDIM  D_                 // 2048

__device__ __forceinline__ float b2f(u16 u) {
    union { unsigned i; float f; } v; v.i = ((unsigned)u) << 16; return v.f;
}
__device__ __forceinline__ u16 f2b(float f) {
    unsigned u = __float_as_uint(f);
    unsigned r = (u + 0x7FFFu + ((u >> 16) & 1u)) >> 16;
    return (u16)r;
}
__device__ __forceinline__ float gelu_exact(float x) {
    return 0.5f * x * (1.0f + erff(x * 0.70710678118654752f));
}

// ---------------------------------------------------------------------------
// Transpose n x n, fp32 in -> bf16 out: out[n0][n1] = bf16(in[n1][n0])
// ---------------------------------------------------------------------------
__global__ void transpose_k(const float* __restrict__ in, u16* __restrict__ out, int n) {
    __shared__ float tile[32][33];
    int bx = blockIdx.x * 32, by = blockIdx.y * 32;
    int tx = threadIdx.x, ty = threadIdx.y;
    for (int i = 0; i < 32; i += 8)
        tile[ty + i][tx] = in[(size_t)(by + ty + i) * n + bx + tx];
    __syncthreads();
    for (int i = 0; i < 32; i += 8)
        out[(size_t)(bx + ty + i) * n + by + tx] = f2b(tile[tx][ty + i]);
}

// ---------------------------------------------------------------------------
// Short conv (fp32 in, bf16 out):
// xs[r,d] = x[r,d] + short_b[d] + sum_j short_w[d,j]*x[t+j-2,d]
// Also zeroes the 12-float w accumulator. 4 elems per thread.
// ---------------------------------------------------------------------------
__global__ void shortconv_k(const float* __restrict__ x, const float* __restrict__ sw,
                            const float* __restrict__ sb, u16* __restrict__ xs,
                            float* __restrict__ wacc) {
    if (blockIdx.x == 0 && threadIdx.x < 12) wacc[threadIdx.x] = 0.0f;
    int gid = blockIdx.x * 256 + threadIdx.x;
    int r = gid >> 9;              // row = b*S + t  (512 threads per row)
    int c = (gid & 511) << 2;      // d0
    int t = r & (S_ - 1);
    const float* base = x + (size_t)r * D_ + c;
    f32x4 cur = *(const f32x4*)base;
    f32x4 m1 = (t >= 1) ? *(const f32x4*)(base - D_) : (f32x4)(0.0f);
    f32x4 m2 = (t >= 2) ? *(const f32x4*)(base - 2 * D_) : (f32x4)(0.0f);
    u16x4 out;
    #pragma unroll
    for (int e = 0; e < 4; ++e) {
        int d = c + e;
        float v = cur[e] + sb[d]
                + sw[d * 3 + 0] * m2[e]
                + sw[d * 3 + 1] * m1[e]
                + sw[d * 3 + 2] * cur[e];
        out[e] = f2b(v);
    }
    *(u16x4*)(xs + (size_t)r * D_ + c) = out;
}

// ---------------------------------------------------------------------------
// GEMM: C[M,N] = act(A[M,K] @ BT[N,K]^T + bias), bf16 A/B, fp32 accum.
// 128x128 tile, BK=32, 256 threads (4 waves 2x2), 4x4 MFMA 16x16x32 per wave.
// OUT_F32 ? fp32 C : bf16 C. bias is fp32.
// ---------------------------------------------------------------------------
template <bool GELU, bool OUT_F32>
__global__ void gemm_k(const u16* __restrict__ A, const u16* __restrict__ BT,
                       const float* __restrict__ bias, void* __restrict__ Cv,
                       int M, int N, int K) {
    __shared__ u16 As[128 * 32];
    __shared__ u16 Bs[128 * 32];
    const int tid = threadIdx.x;
    const int wid = tid >> 6;
    const int lane = tid & 63;
    const int wm = (wid >> 1) * 64;
    const int wn = (wid & 1) * 64;
    const int row0 = blockIdx.y * 128;
    const int col0 = blockIdx.x * 128;

    f32x4 acc[4][4];
    #pragma unroll
    for (int i = 0; i < 4; ++i)
        #pragma unroll
        for (int j = 0; j < 4; ++j) acc[i][j] = (f32x4)(0.0f);

    const int sk = (tid & 3) * 8;
    const int sr = tid >> 2;

    const int mrow = wm + (lane & 15);
    const int nrow = wn + (lane & 15);
    const int k0 = (lane >> 4) * 8;

    for (int kt = 0; kt < K; kt += 32) {
        const u16* ap = A + (size_t)(row0 + sr) * K + kt + sk;
        const u16* bp = BT + (size_t)(col0 + sr) * K + kt + sk;
        u16x8 a0 = *(const u16x8*)(ap);
        u16x8 a1 = *(const u16x8*)(ap + (size_t)64 * K);
        u16x8 b0 = *(const u16x8*)(bp);
        u16x8 b1 = *(const u16x8*)(bp + (size_t)64 * K);
        __syncthreads();   // prior iteration's LDS reads complete
        *(u16x8*)&As[sr * 32 + sk] = a0;
        *(u16x8*)&As[(64 + sr) * 32 + sk] = a1;
        *(u16x8*)&Bs[sr * 32 + sk] = b0;
        *(u16x8*)&Bs[(64 + sr) * 32 + sk] = b1;
        __syncthreads();   // staging visible to all waves

        s16x8 af[4], bfr[4];
        #pragma unroll
        for (int i = 0; i < 4; ++i)
            af[i] = *(const s16x8*)&As[(size_t)(mrow + i * 16) * 32 + k0];
        #pragma unroll
        for (int j = 0; j < 4; ++j)
            bfr[j] = *(const s16x8*)&Bs[(size_t)(nrow + j * 16) * 32 + k0];
        #pragma unroll
        for (int i = 0; i < 4; ++i)
            #pragma unroll
            for (int j = 0; j < 4; ++j)
                acc[i][j] = __builtin_amdgcn_mfma_f32_16x16x32_bf16(
                    af[i], bfr[j], acc[i][j], 0, 0, 0);
    }

    // epilogue: D row = (lane>>4)*4 + r (M dim), col = lane&15 (N dim)
    const int crow0 = row0 + wm + (lane >> 4) * 4;
    const int ccol0 = col0 + wn + (lane & 15);
    #pragma unroll
    for (int j = 0; j < 4; ++j) {
        int col = ccol0 + j * 16;
        float bs = bias[col];
        #pragma unroll
        for (int i = 0; i < 4; ++i) {
            int rbase = crow0 + i * 16;
            #pragma unroll
            for (int r = 0; r < 4; ++r) {
                float v = acc[i][j][r] + bs;
                if (GELU) v = gelu_exact(v);
                if (OUT_F32)
                    ((float*)Cv)[(size_t)(rbase + r) * N + col] = v;
                else
                    ((u16*)Cv)[(size_t)(rbase + r) * N + col] = f2b(v);
            }
        }
    }
}

// ---------------------------------------------------------------------------
// Filter reduce: one wave per (row, f); h is bf16, fw/fb fp32.
// t[k] = sum_i h[row, f*1024+i] * fw[i,k];  atomicAdd tanh(t+fb[k]) into wacc
// ---------------------------------------------------------------------------
__global__ void filt_reduce_k(const u16* __restrict__ h, const float* __restrict__ fw,
                              const float* __restrict__ fb, float* __restrict__ wacc) {
    int wg = (blockIdx.x * 256 + threadIdx.x) >> 6;  // global wave id
    int lane = threadIdx.x & 63;
    int row = wg >> 1;
    int f = wg & 1;
    const u16* hp = h + (size_t)row * D_ + f * DI_ + lane * 16;
    u16x8 h0 = *(const u16x8*)hp;
    u16x8 h1 = *(const u16x8*)(hp + 8);
    u16 hv[16];
    *(u16x8*)(hv) = h0; *(u16x8*)(hv + 8) = h1;
    int i0 = lane * 16;
    float t0 = 0.f, t1 = 0.f, t2 = 0.f;
    #pragma unroll
    for (int j = 0; j < 16; ++j) {
        float hf = b2f(hv[j]);
        int i = i0 + j;
        t0 += hf * fw[i * 3 + 0];
        t1 += hf * fw[i * 3 + 1];
        t2 += hf * fw[i * 3 + 2];
    }
    #pragma unroll
    for (int off = 32; off > 0; off >>= 1) {
        t0 += __shfl_down(t0, off);
        t1 += __shfl_down(t1, off);
        t2 += __shfl_down(t2, off);
    }
    if (lane == 0) {
        int b = row >> 11;  // / S_
        atomicAdd(&wacc[b * 3 + 0], tanhf(t0 + fb[0]));
        atomicAdd(&wacc[b * 3 + 1], tanhf(t1 + fb[1]));
        atomicAdd(&wacc[b * 3 + 2], tanhf(t2 + fb[2]));
    }
}

// ---------------------------------------------------------------------------
// Gate: g[r,d] = gelu( (w0*xs[t-2]+w1*xs[t-1]+w2*xs[t]) * v[r,d] ),  w=wacc/S
// xs bf16, v fp32, g bf16. 4 elems per thread.
// ---------------------------------------------------------------------------
__global__ void gate_k(const u16* __restrict__ xs, const float* __restrict__ v,
                       const float* __restrict__ wacc, u16* __restrict__ g) {
    int gid = blockIdx.x * 256 + threadIdx.x;
    int r = gid >> 9;
    int c = (gid & 511) << 2;
    int t = r & (S_ - 1);
    int b = r >> 11;
    float w0 = wacc[b * 3 + 0] * (1.0f / (float)S_);
    float w1 = wacc[b * 3 + 1] * (1.0f / (float)S_);
    float w2 = wacc[b * 3 + 2] * (1.0f / (float)S_);
    const u16* base = xs + (size_t)r * D_ + c;
    u16x4 cur = *(const u16x4*)base;
    u16x4 m1 = (t >= 1) ? *(const u16x4*)(base - D_) : (u16x4)(0);
    u16x4 m2 = (t >= 2) ? *(const u16x4*)(base - 2 * D_) : (u16x4)(0);
    f32x4 vv = *(const f32x4*)(v + (size_t)r * D_ + c);
    u16x4 out;
    #pragma unroll
    for (int e = 0; e < 4; ++e) {
        float conv = w0 * b2f(m2[e]) + w1 * b2f(m1[e]) + w2 * b2f(cur[e]);
        out[e] = f2b(gelu_exact(conv * vv[e]));
    }
    *(u16x4*)(g + (size_t)r * D_ + c) = out;
}

// ---------------------------------------------------------------------------
extern "C" void kernel_launch(void* const* d_in, const int* in_sizes, int n_in,
                              void* d_out, int out_size, void* d_ws, size_t ws_size,
                              hipStream_t stream) {
    const float* x       = (const float*)d_in[0];
    const float* short_w = (const float*)d_in[1];
    const float* short_b = (const float*)d_in[2];
    const float* proj_w  = (const float*)d_in[3];
    const float* proj_b  = (const float*)d_in[4];
    const float* filt_w  = (const float*)d_in[5];
    const float* filt_b  = (const float*)d_in[6];
    const float* out_w   = (const float*)d_in[7];
    const float* out_b   = (const float*)d_in[8];
    float* out = (float*)d_out;

    // workspace (~72MB): wacc(256B) | xs bf16 32MB | h/g bf16 32MB | wT bf16 8MB
    char* ws = (char*)d_ws;
    const size_t xs_bytes = (size_t)MROWS * D_ * 2;   // 33,554,432
    float* wacc = (float*)(ws);
    u16*   xs   = (u16*)(ws + 256);
    u16*   hg   = (u16*)(ws + 256 + xs_bytes);
    u16*   wT   = (u16*)(ws + 256 + 2 * xs_bytes);    // proj_w^T, then out_w^T

    dim3 tb(32, 8, 1);
    dim3 tg(D_ / 32, D_ / 32, 1);
    transpose_k<<<tg, tb, 0, stream>>>(proj_w, wT, D_);

    int ew_blocks = (MROWS * D_ / 4) / 256;  // 16384
    shortconv_k<<<ew_blocks, 256, 0, stream>>>(x, short_w, short_b, xs, wacc);

    dim3 gg(NDIM / 128, MROWS / 128, 1);     // (16, 64)
    gemm_k<true, false><<<gg, 256, 0, stream>>>(xs, wT, proj_b, hg, MROWS, NDIM, KDIM);

    filt_reduce_k<<<(MROWS * 2) / 4, 256, 0, stream>>>(hg, filt_w, filt_b, wacc);

    transpose_k<<<tg, tb, 0, stream>>>(out_w, wT, D_);  // wT dead after gemm1

    gate_k<<<ew_blocks, 256, 0, stream>>>(xs, x, wacc, hg);  // h dead, reuse as g

    gemm_k<false, true><<<gg, 256, 0, stream>>>(hg, wT, out_b, out, MROWS, NDIM, KDIM);
}

// Round 5
// 400.817 us; speedup vs baseline: 2.5104x; 2.5104x over previous
//
#include <hip/hip_runtime.h>
#include <hip/hip_bf16.h>
#include <math.h>

typedef unsigned short u16;
typedef __attribute__((ext_vector_type(4))) unsigned short u16x4;
typedef __attribute__((ext_vector_type(8))) unsigned short u16x8;
typedef __attribute__((ext_vector_type(8))) short s16x8;
typedef __attribute__((ext_vector_type(4))) float f32x4;

#define B_  4
#define S_  2048
#define D_  2048
#define DI_ 1024
#define MROWS (B_ * S_)          // 8192
#define KDIM  D_                 // 2048
#define NDIM  D_                 // 2048

__device__ __forceinline__ float b2f(u16 u) {
    union { unsigned i; float f; } v; v.i = ((unsigned)u) << 16; return v.f;
}
__device__ __forceinline__ u16 f2b(float f) {
    unsigned u = __float_as_uint(f);
    unsigned r = (u + 0x7FFFu + ((u >> 16) & 1u)) >> 16;
    return (u16)r;
}
__device__ __forceinline__ float gelu_exact(float x) {
    return 0.5f * x * (1.0f + erff(x * 0.70710678118654752f));
}

#define GLOAD_LDS16(gp, lp)                                                    \
    __builtin_amdgcn_global_load_lds(                                          \
        (const __attribute__((address_space(1))) void*)(gp),                   \
        (__attribute__((address_space(3))) void*)(lp), 16, 0, 0)

// ---------------------------------------------------------------------------
// Transpose n x n, fp32 in -> bf16 out: out[n0][n1] = bf16(in[n1][n0])
// ---------------------------------------------------------------------------
__global__ void transpose_k(const float* __restrict__ in, u16* __restrict__ out, int n) {
    __shared__ float tile[32][33];
    int bx = blockIdx.x * 32, by = blockIdx.y * 32;
    int tx = threadIdx.x, ty = threadIdx.y;
    for (int i = 0; i < 32; i += 8)
        tile[ty + i][tx] = in[(size_t)(by + ty + i) * n + bx + tx];
    __syncthreads();
    for (int i = 0; i < 32; i += 8)
        out[(size_t)(bx + ty + i) * n + by + tx] = f2b(tile[tx][ty + i]);
}

// ---------------------------------------------------------------------------
// Short conv (fp32 in, bf16 out):
// xs[r,d] = x[r,d] + short_b[d] + sum_j short_w[d,j]*x[t+j-2,d]
// Also zeroes the 12-float w accumulator. 4 elems per thread.
// ---------------------------------------------------------------------------
__global__ void shortconv_k(const float* __restrict__ x, const float* __restrict__ sw,
                            const float* __restrict__ sb, u16* __restrict__ xs,
                            float* __restrict__ wacc) {
    if (blockIdx.x == 0 && threadIdx.x < 12) wacc[threadIdx.x] = 0.0f;
    int gid = blockIdx.x * 256 + threadIdx.x;
    int r = gid >> 9;              // row = b*S + t  (512 threads per row)
    int c = (gid & 511) << 2;      // d0
    int t = r & (S_ - 1);
    const float* base = x + (size_t)r * D_ + c;
    f32x4 cur = *(const f32x4*)base;
    f32x4 m1 = (t >= 1) ? *(const f32x4*)(base - D_) : (f32x4)(0.0f);
    f32x4 m2 = (t >= 2) ? *(const f32x4*)(base - 2 * D_) : (f32x4)(0.0f);
    u16x4 out;
    #pragma unroll
    for (int e = 0; e < 4; ++e) {
        int d = c + e;
        float v = cur[e] + sb[d]
                + sw[d * 3 + 0] * m2[e]
                + sw[d * 3 + 1] * m1[e]
                + sw[d * 3 + 2] * cur[e];
        out[e] = f2b(v);
    }
    *(u16x4*)(xs + (size_t)r * D_ + c) = out;
}

// ---------------------------------------------------------------------------
// GEMM: C[M,N] = act(A[M,K] @ BT[N,K]^T + bias), bf16 A/B, fp32 accum.
// 128x128 tile, BK=32, 256 threads (4 waves 2x2), 4x4 MFMA 16x16x32 per wave.
// global_load_lds width-16 staging (m97 recipe). OUT_F32 ? fp32 C : bf16 C.
// ---------------------------------------------------------------------------
template <bool GELU, bool OUT_F32>
__global__ void gemm_k(const u16* __restrict__ A, const u16* __restrict__ BT,
                       const float* __restrict__ bias, void* __restrict__ Cv,
                       int M, int N, int K) {
    __shared__ u16 As[128 * 32];
    __shared__ u16 Bs[128 * 32];
    const int tid = threadIdx.x;
    const int wid = tid >> 6;
    const int lane = tid & 63;
    const int wm = (wid >> 1) * 64;
    const int wn = (wid & 1) * 64;
    const int row0 = blockIdx.y * 128;
    const int col0 = blockIdx.x * 128;

    f32x4 acc[4][4];
    #pragma unroll
    for (int i = 0; i < 4; ++i)
        #pragma unroll
        for (int j = 0; j < 4; ++j) acc[i][j] = (f32x4)(0.0f);

    // staging geometry: pass p in {0,1}; wave w covers LDS bytes
    // [(p*4+w)*1024, +1024); lane L lands at base + L*16 ->
    // row = (p*4+w)*16 + L/4, k elems (L%4)*8
    const int srow_l = lane >> 2;
    const int sk = (lane & 3) * 8;

    const int mrow = wm + (lane & 15);
    const int nrow = wn + (lane & 15);
    const int k0 = (lane >> 4) * 8;

    for (int kt = 0; kt < K; kt += 32) {
        __syncthreads();   // prior iteration's LDS reads complete
        #pragma unroll
        for (int p = 0; p < 2; ++p) {
            int srow = p * 64 + wid * 16 + srow_l;
            u16* lpa = &As[(p * 4 + wid) * 512];   // wave-uniform LDS base
            u16* lpb = &Bs[(p * 4 + wid) * 512];
            const u16* ga = A + (size_t)(row0 + srow) * K + kt + sk;
            const u16* gb = BT + (size_t)(col0 + srow) * K + kt + sk;
            GLOAD_LDS16(ga, lpa);
            GLOAD_LDS16(gb, lpb);
        }
        __syncthreads();   // drains vmcnt -> staging visible

        s16x8 af[4], bfr[4];
        #pragma unroll
        for (int i = 0; i < 4; ++i)
            af[i] = *(const s16x8*)&As[(size_t)(mrow + i * 16) * 32 + k0];
        #pragma unroll
        for (int j = 0; j < 4; ++j)
            bfr[j] = *(const s16x8*)&Bs[(size_t)(nrow + j * 16) * 32 + k0];
        #pragma unroll
        for (int i = 0; i < 4; ++i)
            #pragma unroll
            for (int j = 0; j < 4; ++j)
                acc[i][j] = __builtin_amdgcn_mfma_f32_16x16x32_bf16(
                    af[i], bfr[j], acc[i][j], 0, 0, 0);
    }

    // epilogue: D row = (lane>>4)*4 + r (M dim), col = lane&15 (N dim)
    const int crow0 = row0 + wm + (lane >> 4) * 4;
    const int ccol0 = col0 + wn + (lane & 15);
    #pragma unroll
    for (int j = 0; j < 4; ++j) {
        int col = ccol0 + j * 16;
        float bs = bias[col];
        #pragma unroll
        for (int i = 0; i < 4; ++i) {
            int rbase = crow0 + i * 16;
            #pragma unroll
            for (int r = 0; r < 4; ++r) {
                float v = acc[i][j][r] + bs;
                if (GELU) v = gelu_exact(v);
                if (OUT_F32)
                    ((float*)Cv)[(size_t)(rbase + r) * N + col] = v;
                else
                    ((u16*)Cv)[(size_t)(rbase + r) * N + col] = f2b(v);
            }
        }
    }
}

// ---------------------------------------------------------------------------
// Filter reduce, hierarchical. 512 blocks x 256 threads; block handles 16 rows
// (wave w: rows bi*16+w*4 .. +4). Lane: f = lane>>5, i-slice = (lane&31)*32.
// fw slice (96 fp32) preloaded to regs. Per row: 64B h load, 96 FMA,
// width-32 shuffle reduce, tanh at half-leader, LDS accumulate.
// Block emits 3 global atomics.
// ---------------------------------------------------------------------------
__global__ void filt_reduce_k(const u16* __restrict__ h, const float* __restrict__ fw,
                              const float* __restrict__ fb, float* __restrict__ wacc) {
    __shared__ float part[3];
    const int tid = threadIdx.x;
    if (tid < 3) part[tid] = 0.0f;
    __syncthreads();
    const int wid = tid >> 6;
    const int lane = tid & 63;
    const int f = lane >> 5;          // filter order half
    const int j = lane & 31;          // 32-element slice index

    float fwr[96];
    const f32x4* fp4 = (const f32x4*)(fw + (size_t)j * 96);
    #pragma unroll
    for (int e = 0; e < 24; ++e) ((f32x4*)fwr)[e] = fp4[e];
    const float fb0 = fb[0], fb1 = fb[1], fb2 = fb[2];

    const int row0 = blockIdx.x * 16 + wid * 4;
    #pragma unroll
    for (int rr = 0; rr < 4; ++rr) {
        int row = row0 + rr;
        const u16* hp = h + (size_t)row * D_ + f * DI_ + j * 32;
        u16x8 hv[4];
        hv[0] = *(const u16x8*)(hp);
        hv[1] = *(const u16x8*)(hp + 8);
        hv[2] = *(const u16x8*)(hp + 16);
        hv[3] = *(const u16x8*)(hp + 24);
        float t0 = 0.f, t1 = 0.f, t2 = 0.f;
        #pragma unroll
        for (int q = 0; q < 4; ++q)
            #pragma unroll
            for (int e = 0; e < 8; ++e) {
                float hf = b2f(hv[q][e]);
                int ib = (q * 8 + e) * 3;
                t0 += hf * fwr[ib + 0];
                t1 += hf * fwr[ib + 1];
                t2 += hf * fwr[ib + 2];
            }
        #pragma unroll
        for (int off = 16; off > 0; off >>= 1) {
            t0 += __shfl_down(t0, off, 32);
            t1 += __shfl_down(t1, off, 32);
            t2 += __shfl_down(t2, off, 32);
        }
        if (j == 0) {   // lanes 0 (f=0) and 32 (f=1)
            atomicAdd(&part[0], tanhf(t0 + fb0));
            atomicAdd(&part[1], tanhf(t1 + fb1));
            atomicAdd(&part[2], tanhf(t2 + fb2));
        }
    }
    __syncthreads();
    if (tid < 3) {
        int b = blockIdx.x >> 7;      // 128 blocks per batch
        atomicAdd(&wacc[b * 3 + tid], part[tid]);
    }
}

// ---------------------------------------------------------------------------
// Gate: g[r,d] = gelu( (w0*xs[t-2]+w1*xs[t-1]+w2*xs[t]) * v[r,d] ),  w=wacc/S
// xs bf16, v fp32, g bf16. 4 elems per thread.
// ---------------------------------------------------------------------------
__global__ void gate_k(const u16* __restrict__ xs, const float* __restrict__ v,
                       const float* __restrict__ wacc, u16* __restrict__ g) {
    int gid = blockIdx.x * 256 + threadIdx.x;
    int r = gid >> 9;
    int c = (gid & 511) << 2;
    int t = r & (S_ - 1);
    int b = r >> 11;
    float w0 = wacc[b * 3 + 0] * (1.0f / (float)S_);
    float w1 = wacc[b * 3 + 1] * (1.0f / (float)S_);
    float w2 = wacc[b * 3 + 2] * (1.0f / (float)S_);
    const u16* base = xs + (size_t)r * D_ + c;
    u16x4 cur = *(const u16x4*)base;
    u16x4 m1 = (t >= 1) ? *(const u16x4*)(base - D_) : (u16x4)(0);
    u16x4 m2 = (t >= 2) ? *(const u16x4*)(base - 2 * D_) : (u16x4)(0);
    f32x4 vv = *(const f32x4*)(v + (size_t)r * D_ + c);
    u16x4 out;
    #pragma unroll
    for (int e = 0; e < 4; ++e) {
        float conv = w0 * b2f(m2[e]) + w1 * b2f(m1[e]) + w2 * b2f(cur[e]);
        out[e] = f2b(gelu_exact(conv * vv[e]));
    }
    *(u16x4*)(g + (size_t)r * D_ + c) = out;
}

// ---------------------------------------------------------------------------
extern "C" void kernel_launch(void* const* d_in, const int* in_sizes, int n_in,
                              void* d_out, int out_size, void* d_ws, size_t ws_size,
                              hipStream_t stream) {
    const float* x       = (const float*)d_in[0];
    const float* short_w = (const float*)d_in[1];
    const float* short_b = (const float*)d_in[2];
    const float* proj_w  = (const float*)d_in[3];
    const float* proj_b  = (const float*)d_in[4];
    const float* filt_w  = (const float*)d_in[5];
    const float* filt_b  = (const float*)d_in[6];
    const float* out_w   = (const float*)d_in[7];
    const float* out_b   = (const float*)d_in[8];
    float* out = (float*)d_out;

    // workspace (~72MB): wacc(256B) | xs bf16 32MB | h/g bf16 32MB | wT bf16 8MB
    char* ws = (char*)d_ws;
    const size_t xs_bytes = (size_t)MROWS * D_ * 2;   // 33,554,432
    float* wacc = (float*)(ws);
    u16*   xs   = (u16*)(ws + 256);
    u16*   hg   = (u16*)(ws + 256 + xs_bytes);
    u16*   wT   = (u16*)(ws + 256 + 2 * xs_bytes);    // proj_w^T, then out_w^T

    dim3 tb(32, 8, 1);
    dim3 tg(D_ / 32, D_ / 32, 1);
    transpose_k<<<tg, tb, 0, stream>>>(proj_w, wT, D_);

    int ew_blocks = (MROWS * D_ / 4) / 256;  // 16384
    shortconv_k<<<ew_blocks, 256, 0, stream>>>(x, short_w, short_b, xs, wacc);

    dim3 gg(NDIM / 128, MROWS / 128, 1);     // (16, 64)
    gemm_k<true, false><<<gg, 256, 0, stream>>>(xs, wT, proj_b, hg, MROWS, NDIM, KDIM);

    filt_reduce_k<<<512, 256, 0, stream>>>(hg, filt_w, filt_b, wacc);

    transpose_k<<<tg, tb, 0, stream>>>(out_w, wT, D_);  // wT dead after gemm1

    gate_k<<<ew_blocks, 256, 0, stream>>>(xs, x, wacc, hg);  // h dead, reuse as g

    gemm_k<false, true><<<gg, 256, 0, stream>>>(hg, wT, out_b, out, MROWS, NDIM, KDIM);
}

// Round 6
// 392.706 us; speedup vs baseline: 2.5623x; 1.0207x over previous
//
#include <hip/hip_runtime.h>
#include <hip/hip_bf16.h>
#include <math.h>

typedef unsigned short u16;
typedef __attribute__((ext_vector_type(4))) unsigned short u16x4;
typedef __attribute__((ext_vector_type(8))) unsigned short u16x8;
typedef __attribute__((ext_vector_type(8))) short s16x8;
typedef __attribute__((ext_vector_type(4))) float f32x4;

#define B_  4
#define S_  2048
#define D_  2048
#define DI_ 1024
#define MROWS (B_ * S_)          // 8192
#define KDIM  D_                 // 2048
#define NDIM  D_                 // 2048

__device__ __forceinline__ float b2f(u16 u) {
    union { unsigned i; float f; } v; v.i = ((unsigned)u) << 16; return v.f;
}
__device__ __forceinline__ u16 f2b(float f) {
    unsigned u = __float_as_uint(f);
    unsigned r = (u + 0x7FFFu + ((u >> 16) & 1u)) >> 16;
    return (u16)r;
}
__device__ __forceinline__ float gelu_exact(float x) {
    return 0.5f * x * (1.0f + erff(x * 0.70710678118654752f));
}

#define GLOAD_LDS16(gp, lp)                                                    \
    __builtin_amdgcn_global_load_lds(                                          \
        (const __attribute__((address_space(1))) void*)(gp),                   \
        (__attribute__((address_space(3))) void*)(lp), 16, 0, 0)

// ---------------------------------------------------------------------------
// Transpose n x n, fp32 in -> bf16 out: out[n0][n1] = bf16(in[n1][n0])
// ---------------------------------------------------------------------------
__global__ void transpose_k(const float* __restrict__ in, u16* __restrict__ out, int n) {
    __shared__ float tile[32][33];
    int bx = blockIdx.x * 32, by = blockIdx.y * 32;
    int tx = threadIdx.x, ty = threadIdx.y;
    for (int i = 0; i < 32; i += 8)
        tile[ty + i][tx] = in[(size_t)(by + ty + i) * n + bx + tx];
    __syncthreads();
    for (int i = 0; i < 32; i += 8)
        out[(size_t)(bx + ty + i) * n + by + tx] = f2b(tile[tx][ty + i]);
}

// ---------------------------------------------------------------------------
// Short conv (fp32 in, bf16 out):
// xs[r,d] = x[r,d] + short_b[d] + sum_j short_w[d,j]*x[t+j-2,d]
// Also zeroes wacc (12 floats) and t_g (49152 floats).
// ---------------------------------------------------------------------------
__global__ void shortconv_k(const float* __restrict__ x, const float* __restrict__ sw,
                            const float* __restrict__ sb, u16* __restrict__ xs,
                            float* __restrict__ wacc, float* __restrict__ t_g) {
    if (blockIdx.x == 0 && threadIdx.x < 12) wacc[threadIdx.x] = 0.0f;
    if (blockIdx.x < 192) {
        int z = blockIdx.x * 256 + threadIdx.x;   // < 49152
        t_g[z] = 0.0f;
    }
    int gid = blockIdx.x * 256 + threadIdx.x;
    int r = gid >> 9;              // row = b*S + t  (512 threads per row)
    int c = (gid & 511) << 2;      // d0
    int t = r & (S_ - 1);
    const float* base = x + (size_t)r * D_ + c;
    f32x4 cur = *(const f32x4*)base;
    f32x4 m1 = (t >= 1) ? *(const f32x4*)(base - D_) : (f32x4)(0.0f);
    f32x4 m2 = (t >= 2) ? *(const f32x4*)(base - 2 * D_) : (f32x4)(0.0f);
    u16x4 out;
    #pragma unroll
    for (int e = 0; e < 4; ++e) {
        int d = c + e;
        float v = cur[e] + sb[d]
                + sw[d * 3 + 0] * m2[e]
                + sw[d * 3 + 1] * m1[e]
                + sw[d * 3 + 2] * cur[e];
        out[e] = f2b(v);
    }
    *(u16x4*)(xs + (size_t)r * D_ + c) = out;
}

// ---------------------------------------------------------------------------
// GEMM: 128x128 tile, BK=32, 4 waves (2x2), 4x4 MFMA 16x16x32 per wave.
// global_load_lds width-16 staging with XOR k-chunk swizzle:
//   LDS slot (row, cs) holds global chunk cs ^ ((row>>1)&3)  -> 2-way banks.
// FILT=true  (GEMM1): no C write; epilogue computes gelu(acc+bias), folds
//   with fw into per-row partial dot t[row][f][k], atomics into t_g.
// FILT=false (GEMM2): C fp32 = acc + bias.
// ---------------------------------------------------------------------------
template <bool FILT>
__global__ void gemm_k(const u16* __restrict__ A, const u16* __restrict__ BT,
                       const float* __restrict__ bias, float* __restrict__ C,
                       const float* __restrict__ fw, float* __restrict__ t_g,
                       int M, int N, int K) {
    __shared__ u16 As[128 * 32];
    __shared__ u16 Bs[128 * 32];
    __shared__ float t_lds[128 * 3];
    const int tid = threadIdx.x;
    const int wid = tid >> 6;
    const int lane = tid & 63;
    const int wm = (wid >> 1) * 64;
    const int wn = (wid & 1) * 64;
    const int row0 = blockIdx.y * 128;
    const int col0 = blockIdx.x * 128;

    if (FILT) {
        for (int z = tid; z < 384; z += 256) t_lds[z] = 0.0f;
    }

    f32x4 acc[4][4];
    #pragma unroll
    for (int i = 0; i < 4; ++i)
        #pragma unroll
        for (int j = 0; j < 4; ++j) acc[i][j] = (f32x4)(0.0f);

    const int srow_l = lane >> 2;     // row within 16-row staging slab
    const int cs = lane & 3;          // LDS slot chunk

    const int mrow = wm + (lane & 15);
    const int nrow = wn + (lane & 15);
    const int cf = lane >> 4;         // fragment k-chunk (k0 = cf*8)

    for (int kt = 0; kt < K; kt += 32) {
        __syncthreads();   // prior iteration's LDS reads complete
        #pragma unroll
        for (int p = 0; p < 2; ++p) {
            int srow = p * 64 + wid * 16 + srow_l;
            int gc = cs ^ ((srow >> 1) & 3);       // global chunk for this slot
            u16* lpa = &As[(p * 4 + wid) * 512];   // wave-uniform LDS base
            u16* lpb = &Bs[(p * 4 + wid) * 512];
            const u16* ga = A + (size_t)(row0 + srow) * K + kt + gc * 8;
            const u16* gb = BT + (size_t)(col0 + srow) * K + kt + gc * 8;
            GLOAD_LDS16(ga, lpa);
            GLOAD_LDS16(gb, lpb);
        }
        __syncthreads();   // drains vmcnt -> staging visible

        s16x8 af[4], bfr[4];
        #pragma unroll
        for (int i = 0; i < 4; ++i) {
            int ra = mrow + i * 16;
            af[i] = *(const s16x8*)&As[ra * 32 + ((cf ^ ((ra >> 1) & 3)) * 8)];
        }
        #pragma unroll
        for (int j = 0; j < 4; ++j) {
            int rb = nrow + j * 16;
            bfr[j] = *(const s16x8*)&Bs[rb * 32 + ((cf ^ ((rb >> 1) & 3)) * 8)];
        }
        #pragma unroll
        for (int i = 0; i < 4; ++i)
            #pragma unroll
            for (int j = 0; j < 4; ++j)
                acc[i][j] = __builtin_amdgcn_mfma_f32_16x16x32_bf16(
                    af[i], bfr[j], acc[i][j], 0, 0, 0);
    }

    // C/D layout: row = wm + (lane>>4)*4 + i*16 + r, col = wn + (lane&15) + j*16
    const int colt0 = wn + (lane & 15);
    if (FILT) {
        float fwv[4][3], bsv[4];
        const int ibase = (col0 & (DI_ - 1)) + colt0;
        #pragma unroll
        for (int j = 0; j < 4; ++j) {
            int ifilt = ibase + j * 16;
            fwv[j][0] = fw[ifilt * 3 + 0];
            fwv[j][1] = fw[ifilt * 3 + 1];
            fwv[j][2] = fw[ifilt * 3 + 2];
            bsv[j] = bias[col0 + colt0 + j * 16];
        }
        #pragma unroll
        for (int i = 0; i < 4; ++i) {
            #pragma unroll
            for (int r = 0; r < 4; ++r) {
                float s0 = 0.f, s1 = 0.f, s2 = 0.f;
                #pragma unroll
                for (int j = 0; j < 4; ++j) {
                    float hv = gelu_exact(acc[i][j][r] + bsv[j]);
                    s0 += hv * fwv[j][0];
                    s1 += hv * fwv[j][1];
                    s2 += hv * fwv[j][2];
                }
                #pragma unroll
                for (int m = 1; m < 16; m <<= 1) {
                    s0 += __shfl_xor(s0, m, 16);
                    s1 += __shfl_xor(s1, m, 16);
                    s2 += __shfl_xor(s2, m, 16);
                }
                if ((lane & 15) == 0) {
                    int trow = wm + (lane >> 4) * 4 + i * 16 + r;
                    atomicAdd(&t_lds[trow * 3 + 0], s0);
                    atomicAdd(&t_lds[trow * 3 + 1], s1);
                    atomicAdd(&t_lds[trow * 3 + 2], s2);
                }
            }
        }
        __syncthreads();
        const int f3 = (col0 >= DI_) ? 3 : 0;
        for (int z = tid; z < 384; z += 256) {
            int rr = z / 3, k = z - rr * 3;
            atomicAdd(&t_g[(size_t)(row0 + rr) * 6 + f3 + k], t_lds[z]);
        }
    } else {
        const int crow0 = row0 + wm + (lane >> 4) * 4;
        #pragma unroll
        for (int j = 0; j < 4; ++j) {
            int col = col0 + colt0 + j * 16;
            float bs = bias[col];
            #pragma unroll
            for (int i = 0; i < 4; ++i) {
                int rbase = crow0 + i * 16;
                #pragma unroll
                for (int r = 0; r < 4; ++r)
                    C[(size_t)(rbase + r) * N + col] = acc[i][j][r] + bs;
            }
        }
    }
}

// ---------------------------------------------------------------------------
// Filt finish: 64 blocks x 256. Thread -> pair p (row = p>>1, f = p&1):
// tanh(t_g[row][f][k] + fb[k]) -> LDS part -> 3 global atomics per block.
// ---------------------------------------------------------------------------
__global__ void filt_finish_k(const float* __restrict__ t_g, const float* __restrict__ fb,
                              float* __restrict__ wacc) {
    __shared__ float part[3];
    const int tid = threadIdx.x;
    if (tid < 3) part[tid] = 0.0f;
    __syncthreads();
    int p = blockIdx.x * 256 + tid;
    int row = p >> 1, f = p & 1;
    const float* tp = t_g + (size_t)row * 6 + f * 3;
    atomicAdd(&part[0], tanhf(tp[0] + fb[0]));
    atomicAdd(&part[1], tanhf(tp[1] + fb[1]));
    atomicAdd(&part[2], tanhf(tp[2] + fb[2]));
    __syncthreads();
    if (tid < 3) {
        int b = blockIdx.x >> 4;     // 16 blocks per batch (2048 rows / 128)
        atomicAdd(&wacc[b * 3 + tid], part[tid]);
    }
}

// ---------------------------------------------------------------------------
// Gate: g[r,d] = gelu( (w0*xs[t-2]+w1*xs[t-1]+w2*xs[t]) * v[r,d] ),  w=wacc/S
// ---------------------------------------------------------------------------
__global__ void gate_k(const u16* __restrict__ xs, const float* __restrict__ v,
                       const float* __restrict__ wacc, u16* __restrict__ g) {
    int gid = blockIdx.x * 256 + threadIdx.x;
    int r = gid >> 9;
    int c = (gid & 511) << 2;
    int t = r & (S_ - 1);
    int b = r >> 11;
    float w0 = wacc[b * 3 + 0] * (1.0f / (float)S_);
    float w1 = wacc[b * 3 + 1] * (1.0f / (float)S_);
    float w2 = wacc[b * 3 + 2] * (1.0f / (float)S_);
    const u16* base = xs + (size_t)r * D_ + c;
    u16x4 cur = *(const u16x4*)base;
    u16x4 m1 = (t >= 1) ? *(const u16x4*)(base - D_) : (u16x4)(0);
    u16x4 m2 = (t >= 2) ? *(const u16x4*)(base - 2 * D_) : (u16x4)(0);
    f32x4 vv = *(const f32x4*)(v + (size_t)r * D_ + c);
    u16x4 out;
    #pragma unroll
    for (int e = 0; e < 4; ++e) {
        float conv = w0 * b2f(m2[e]) + w1 * b2f(m1[e]) + w2 * b2f(cur[e]);
        out[e] = f2b(gelu_exact(conv * vv[e]));
    }
    *(u16x4*)(g + (size_t)r * D_ + c) = out;
}

// ---------------------------------------------------------------------------
extern "C" void kernel_launch(void* const* d_in, const int* in_sizes, int n_in,
                              void* d_out, int out_size, void* d_ws, size_t ws_size,
                              hipStream_t stream) {
    const float* x       = (const float*)d_in[0];
    const float* short_w = (const float*)d_in[1];
    const float* short_b = (const float*)d_in[2];
    const float* proj_w  = (const float*)d_in[3];
    const float* proj_b  = (const float*)d_in[4];
    const float* filt_w  = (const float*)d_in[5];
    const float* filt_b  = (const float*)d_in[6];
    const float* out_w   = (const float*)d_in[7];
    const float* out_b   = (const float*)d_in[8];
    float* out = (float*)d_out;

    // ws (~72.6MB): wacc | t_g 192KB | xs bf16 32MB | g bf16 32MB | wT bf16 8MB
    char* ws = (char*)d_ws;
    const size_t xs_bytes = (size_t)MROWS * D_ * 2;   // 33,554,432
    float* wacc = (float*)(ws);
    float* t_g  = (float*)(ws + 1024);                // 8192*6 fp32 = 196,608 B
    u16*   xs   = (u16*)(ws + 262144);
    u16*   g    = (u16*)(ws + 262144 + xs_bytes);
    u16*   wT   = (u16*)(ws + 262144 + 2 * xs_bytes); // proj_w^T, then out_w^T

    dim3 tb(32, 8, 1);
    dim3 tg(D_ / 32, D_ / 32, 1);
    transpose_k<<<tg, tb, 0, stream>>>(proj_w, wT, D_);

    int ew_blocks = (MROWS * D_ / 4) / 256;  // 16384
    shortconv_k<<<ew_blocks, 256, 0, stream>>>(x, short_w, short_b, xs, wacc, t_g);

    dim3 gg(NDIM / 128, MROWS / 128, 1);     // (16, 64)
    gemm_k<true><<<gg, 256, 0, stream>>>(xs, wT, proj_b, nullptr, filt_w, t_g,
                                         MROWS, NDIM, KDIM);

    filt_finish_k<<<64, 256, 0, stream>>>(t_g, filt_b, wacc);

    transpose_k<<<tg, tb, 0, stream>>>(out_w, wT, D_);  // wT dead after gemm1

    gate_k<<<ew_blocks, 256, 0, stream>>>(xs, x, wacc, g);

    gemm_k<false><<<gg, 256, 0, stream>>>(g, wT, out_b, out, nullptr, nullptr,
                                          MROWS, NDIM, KDIM);
}

// Round 7
// 377.700 us; speedup vs baseline: 2.6641x; 1.0397x over previous
//
#include <hip/hip_runtime.h>
#include <hip/hip_bf16.h>
#include <math.h>

typedef unsigned short u16;
typedef __attribute__((ext_vector_type(4))) unsigned short u16x4;
typedef __attribute__((ext_vector_type(8))) unsigned short u16x8;
typedef __attribute__((ext_vector_type(8))) short s16x8;
typedef __attribute__((ext_vector_type(4))) float f32x4;

#define B_  4
#define S_  2048
#define D_  2048
#define DI_ 1024
#define MROWS (B_ * S_)          // 8192
#define KDIM  D_                 // 2048
#define NDIM  D_                 // 2048
#define STRIP 16                 // rows per conv strip (divides S_)

__device__ __forceinline__ float b2f(u16 u) {
    union { unsigned i; float f; } v; v.i = ((unsigned)u) << 16; return v.f;
}
__device__ __forceinline__ u16 f2b(float f) {
    unsigned u = __float_as_uint(f);
    unsigned r = (u + 0x7FFFu + ((u >> 16) & 1u)) >> 16;
    return (u16)r;
}
__device__ __forceinline__ float gelu_exact(float x) {
    return 0.5f * x * (1.0f + erff(x * 0.70710678118654752f));
}

#define GLOAD_LDS16(gp, lp)                                                    \
    __builtin_amdgcn_global_load_lds(                                          \
        (const __attribute__((address_space(1))) void*)(gp),                   \
        (__attribute__((address_space(3))) void*)(lp), 16, 0, 0)

// ---------------------------------------------------------------------------
// Transpose n x n, fp32 in -> bf16 out. DUAL=true: blockIdx.z picks src/dst.
// ---------------------------------------------------------------------------
__global__ void transpose_k(const float* __restrict__ in0, u16* __restrict__ out0,
                            const float* __restrict__ in1, u16* __restrict__ out1,
                            int n) {
    __shared__ float tile[32][33];
    const float* in = (blockIdx.z == 0) ? in0 : in1;
    u16* out = (blockIdx.z == 0) ? out0 : out1;
    int bx = blockIdx.x * 32, by = blockIdx.y * 32;
    int tx = threadIdx.x, ty = threadIdx.y;
    for (int i = 0; i < 32; i += 8)
        tile[ty + i][tx] = in[(size_t)(by + ty + i) * n + bx + tx];
    __syncthreads();
    for (int i = 0; i < 32; i += 8)
        out[(size_t)(bx + ty + i) * n + by + tx] = f2b(tile[tx][ty + i]);
}

// ---------------------------------------------------------------------------
// Short conv, strip-mined (fp32 in, bf16 out):
// grid (2, MROWS/STRIP); thread owns cols c..c+3 for STRIP consecutive rows,
// carrying taps m1/m2 in registers (each row read ~1.125x instead of 3x).
// Also zeroes wacc (12 floats) and t_g (49152 floats).
// ---------------------------------------------------------------------------
__global__ void shortconv_k(const float* __restrict__ x, const float* __restrict__ sw,
                            const float* __restrict__ sb, u16* __restrict__ xs,
                            float* __restrict__ wacc, float* __restrict__ t_g) {
    const int bid = blockIdx.y * 2 + blockIdx.x;
    {
        int z = bid * 256 + threadIdx.x;
        if (z < 12) wacc[z] = 0.0f;
        if (z < MROWS * 6) t_g[z] = 0.0f;
    }
    const int c = blockIdx.x * 1024 + threadIdx.x * 4;
    const int r0 = blockIdx.y * STRIP;
    const int t0 = r0 & (S_ - 1);

    // 4 cols x 3 taps = 12 contiguous floats at sw[c*3]
    float tap[12];
    #pragma unroll
    for (int q = 0; q < 3; ++q)
        ((f32x4*)tap)[q] = *(const f32x4*)(sw + (size_t)c * 3 + q * 4);
    f32x4 sbv = *(const f32x4*)(sb + c);

    const float* base = x + (size_t)r0 * D_ + c;
    f32x4 m2, m1;
    if (t0 == 0) { m2 = (f32x4)(0.0f); m1 = (f32x4)(0.0f); }
    else { m2 = *(const f32x4*)(base - 2 * D_); m1 = *(const f32x4*)(base - D_); }

    u16* op = xs + (size_t)r0 * D_ + c;
    #pragma unroll
    for (int rr = 0; rr < STRIP; ++rr) {
        f32x4 cur = *(const f32x4*)(base + (size_t)rr * D_);
        u16x4 outv;
        #pragma unroll
        for (int e = 0; e < 4; ++e) {
            float v = cur[e] + sbv[e]
                    + tap[e * 3 + 0] * m2[e]
                    + tap[e * 3 + 1] * m1[e]
                    + tap[e * 3 + 2] * cur[e];
            outv[e] = f2b(v);
        }
        *(u16x4*)(op + (size_t)rr * D_) = outv;
        m2 = m1; m1 = cur;
    }
}

// ---------------------------------------------------------------------------
// GEMM: 128x128 tile, BK=32, 4 waves (2x2), 4x4 MFMA 16x16x32 per wave.
// global_load_lds width-16 staging with XOR k-chunk swizzle.
// FILT=true  (GEMM1): no C write; epilogue folds gelu(acc+bias) with fw into
//   per-row partials t_g. FILT=false (GEMM2): C fp32 = acc + bias.
// ---------------------------------------------------------------------------
template <bool FILT>
__global__ void gemm_k(const u16* __restrict__ A, const u16* __restrict__ BT,
                       const float* __restrict__ bias, float* __restrict__ C,
                       const float* __restrict__ fw, float* __restrict__ t_g,
                       int M, int N, int K) {
    __shared__ u16 As[128 * 32];
    __shared__ u16 Bs[128 * 32];
    __shared__ float t_lds[128 * 3];
    const int tid = threadIdx.x;
    const int wid = tid >> 6;
    const int lane = tid & 63;
    const int wm = (wid >> 1) * 64;
    const int wn = (wid & 1) * 64;
    const int row0 = blockIdx.y * 128;
    const int col0 = blockIdx.x * 128;

    if (FILT) {
        for (int z = tid; z < 384; z += 256) t_lds[z] = 0.0f;
    }

    f32x4 acc[4][4];
    #pragma unroll
    for (int i = 0; i < 4; ++i)
        #pragma unroll
        for (int j = 0; j < 4; ++j) acc[i][j] = (f32x4)(0.0f);

    const int srow_l = lane >> 2;     // row within 16-row staging slab
    const int cs = lane & 3;          // LDS slot chunk

    const int mrow = wm + (lane & 15);
    const int nrow = wn + (lane & 15);
    const int cf = lane >> 4;         // fragment k-chunk (k0 = cf*8)

    for (int kt = 0; kt < K; kt += 32) {
        __syncthreads();   // prior iteration's LDS reads complete
        #pragma unroll
        for (int p = 0; p < 2; ++p) {
            int srow = p * 64 + wid * 16 + srow_l;
            int gc = cs ^ ((srow >> 1) & 3);       // global chunk for this slot
            u16* lpa = &As[(p * 4 + wid) * 512];   // wave-uniform LDS base
            u16* lpb = &Bs[(p * 4 + wid) * 512];
            const u16* ga = A + (size_t)(row0 + srow) * K + kt + gc * 8;
            const u16* gb = BT + (size_t)(col0 + srow) * K + kt + gc * 8;
            GLOAD_LDS16(ga, lpa);
            GLOAD_LDS16(gb, lpb);
        }
        __syncthreads();   // drains vmcnt -> staging visible

        s16x8 af[4], bfr[4];
        #pragma unroll
        for (int i = 0; i < 4; ++i) {
            int ra = mrow + i * 16;
            af[i] = *(const s16x8*)&As[ra * 32 + ((cf ^ ((ra >> 1) & 3)) * 8)];
        }
        #pragma unroll
        for (int j = 0; j < 4; ++j) {
            int rb = nrow + j * 16;
            bfr[j] = *(const s16x8*)&Bs[rb * 32 + ((cf ^ ((rb >> 1) & 3)) * 8)];
        }
        #pragma unroll
        for (int i = 0; i < 4; ++i)
            #pragma unroll
            for (int j = 0; j < 4; ++j)
                acc[i][j] = __builtin_amdgcn_mfma_f32_16x16x32_bf16(
                    af[i], bfr[j], acc[i][j], 0, 0, 0);
    }

    // C/D layout: row = wm + (lane>>4)*4 + i*16 + r, col = wn + (lane&15) + j*16
    const int colt0 = wn + (lane & 15);
    if (FILT) {
        float fwv[4][3], bsv[4];
        const int ibase = (col0 & (DI_ - 1)) + colt0;
        #pragma unroll
        for (int j = 0; j < 4; ++j) {
            int ifilt = ibase + j * 16;
            fwv[j][0] = fw[ifilt * 3 + 0];
            fwv[j][1] = fw[ifilt * 3 + 1];
            fwv[j][2] = fw[ifilt * 3 + 2];
            bsv[j] = bias[col0 + colt0 + j * 16];
        }
        #pragma unroll
        for (int i = 0; i < 4; ++i) {
            #pragma unroll
            for (int r = 0; r < 4; ++r) {
                float s0 = 0.f, s1 = 0.f, s2 = 0.f;
                #pragma unroll
                for (int j = 0; j < 4; ++j) {
                    float hv = gelu_exact(acc[i][j][r] + bsv[j]);
                    s0 += hv * fwv[j][0];
                    s1 += hv * fwv[j][1];
                    s2 += hv * fwv[j][2];
                }
                #pragma unroll
                for (int m = 1; m < 16; m <<= 1) {
                    s0 += __shfl_xor(s0, m, 16);
                    s1 += __shfl_xor(s1, m, 16);
                    s2 += __shfl_xor(s2, m, 16);
                }
                if ((lane & 15) == 0) {
                    int trow = wm + (lane >> 4) * 4 + i * 16 + r;
                    atomicAdd(&t_lds[trow * 3 + 0], s0);
                    atomicAdd(&t_lds[trow * 3 + 1], s1);
                    atomicAdd(&t_lds[trow * 3 + 2], s2);
                }
            }
        }
        __syncthreads();
        const int f3 = (col0 >= DI_) ? 3 : 0;
        for (int z = tid; z < 384; z += 256) {
            int rr = z / 3, k = z - rr * 3;
            atomicAdd(&t_g[(size_t)(row0 + rr) * 6 + f3 + k], t_lds[z]);
        }
    } else {
        const int crow0 = row0 + wm + (lane >> 4) * 4;
        #pragma unroll
        for (int j = 0; j < 4; ++j) {
            int col = col0 + colt0 + j * 16;
            float bs = bias[col];
            #pragma unroll
            for (int i = 0; i < 4; ++i) {
                int rbase = crow0 + i * 16;
                #pragma unroll
                for (int r = 0; r < 4; ++r)
                    C[(size_t)(rbase + r) * N + col] = acc[i][j][r] + bs;
            }
        }
    }
}

// ---------------------------------------------------------------------------
// Filt finish: 64 blocks x 256. Thread -> pair p (row = p>>1, f = p&1):
// tanh(t_g[row][f][k] + fb[k]) -> LDS part -> 3 global atomics per block.
// ---------------------------------------------------------------------------
__global__ void filt_finish_k(const float* __restrict__ t_g, const float* __restrict__ fb,
                              float* __restrict__ wacc) {
    __shared__ float part[3];
    const int tid = threadIdx.x;
    if (tid < 3) part[tid] = 0.0f;
    __syncthreads();
    int p = blockIdx.x * 256 + tid;
    int row = p >> 1, f = p & 1;
    const float* tp = t_g + (size_t)row * 6 + f * 3;
    atomicAdd(&part[0], tanhf(tp[0] + fb[0]));
    atomicAdd(&part[1], tanhf(tp[1] + fb[1]));
    atomicAdd(&part[2], tanhf(tp[2] + fb[2]));
    __syncthreads();
    if (tid < 3) {
        int b = blockIdx.x >> 4;     // 16 blocks per batch
        atomicAdd(&wacc[b * 3 + tid], part[tid]);
    }
}

// ---------------------------------------------------------------------------
// Gate, strip-mined: g[r,d] = gelu(conv3_w(xs)[r,d] * v[r,d]), w = wacc/S.
// Same strip geometry as shortconv_k; taps carried in registers.
// ---------------------------------------------------------------------------
__global__ void gate_k(const u16* __restrict__ xs, const float* __restrict__ v,
                       const float* __restrict__ wacc, u16* __restrict__ g) {
    const int c = blockIdx.x * 1024 + threadIdx.x * 4;
    const int r0 = blockIdx.y * STRIP;
    const int t0 = r0 & (S_ - 1);
    const int b = r0 >> 11;
    const float w0 = wacc[b * 3 + 0] * (1.0f / (float)S_);
    const float w1 = wacc[b * 3 + 1] * (1.0f / (float)S_);
    const float w2 = wacc[b * 3 + 2] * (1.0f / (float)S_);

    const u16* base = xs + (size_t)r0 * D_ + c;
    f32x4 m2, m1;
    if (t0 == 0) {
        m2 = (f32x4)(0.0f); m1 = (f32x4)(0.0f);
    } else {
        u16x4 a2 = *(const u16x4*)(base - 2 * D_);
        u16x4 a1 = *(const u16x4*)(base - D_);
        #pragma unroll
        for (int e = 0; e < 4; ++e) { m2[e] = b2f(a2[e]); m1[e] = b2f(a1[e]); }
    }

    const float* vp = v + (size_t)r0 * D_ + c;
    u16* op = g + (size_t)r0 * D_ + c;
    #pragma unroll
    for (int rr = 0; rr < STRIP; ++rr) {
        u16x4 cb = *(const u16x4*)(base + (size_t)rr * D_);
        f32x4 vv = *(const f32x4*)(vp + (size_t)rr * D_);
        f32x4 cur;
        #pragma unroll
        for (int e = 0; e < 4; ++e) cur[e] = b2f(cb[e]);
        u16x4 outv;
        #pragma unroll
        for (int e = 0; e < 4; ++e) {
            float conv = w0 * m2[e] + w1 * m1[e] + w2 * cur[e];
            outv[e] = f2b(gelu_exact(conv * vv[e]));
        }
        *(u16x4*)(op + (size_t)rr * D_) = outv;
        m2 = m1; m1 = cur;
    }
}

// ---------------------------------------------------------------------------
extern "C" void kernel_launch(void* const* d_in, const int* in_sizes, int n_in,
                              void* d_out, int out_size, void* d_ws, size_t ws_size,
                              hipStream_t stream) {
    const float* x       = (const float*)d_in[0];
    const float* short_w = (const float*)d_in[1];
    const float* short_b = (const float*)d_in[2];
    const float* proj_w  = (const float*)d_in[3];
    const float* proj_b  = (const float*)d_in[4];
    const float* filt_w  = (const float*)d_in[5];
    const float* filt_b  = (const float*)d_in[6];
    const float* out_w   = (const float*)d_in[7];
    const float* out_b   = (const float*)d_in[8];
    float* out = (float*)d_out;

    // ws: wacc | t_g | xs bf16 32MB | g bf16 32MB | wT1 8MB [| wT2 8MB]
    char* ws = (char*)d_ws;
    const size_t xs_bytes = (size_t)MROWS * D_ * 2;   // 33,554,432
    const size_t wt_bytes = (size_t)KDIM * NDIM * 2;  // 8,388,608
    float* wacc = (float*)(ws);
    float* t_g  = (float*)(ws + 1024);                // 8192*6 fp32
    u16*   xs   = (u16*)(ws + 262144);
    u16*   g    = (u16*)(ws + 262144 + xs_bytes);
    u16*   wT1  = (u16*)(ws + 262144 + 2 * xs_bytes);
    const size_t need_dual = 262144 + 2 * xs_bytes + 2 * wt_bytes;
    const bool dual = (ws_size >= need_dual);
    u16* wT2 = dual ? (u16*)(ws + 262144 + 2 * xs_bytes + wt_bytes) : wT1;

    dim3 tb(32, 8, 1);

    if (dual) {
        dim3 tg(D_ / 32, D_ / 32, 2);
        transpose_k<<<tg, tb, 0, stream>>>(proj_w, wT1, out_w, wT2, D_);
    } else {
        dim3 tg(D_ / 32, D_ / 32, 1);
        transpose_k<<<tg, tb, 0, stream>>>(proj_w, wT1, proj_w, wT1, D_);
    }

    dim3 cg(2, MROWS / STRIP, 1);   // 1024 blocks
    shortconv_k<<<cg, 256, 0, stream>>>(x, short_w, short_b, xs, wacc, t_g);

    dim3 gg(NDIM / 128, MROWS / 128, 1);     // (16, 64)
    gemm_k<true><<<gg, 256, 0, stream>>>(xs, wT1, proj_b, nullptr, filt_w, t_g,
                                         MROWS, NDIM, KDIM);

    filt_finish_k<<<64, 256, 0, stream>>>(t_g, filt_b, wacc);

    if (!dual) {
        dim3 tg(D_ / 32, D_ / 32, 1);
        transpose_k<<<tg, tb, 0, stream>>>(out_w, wT2, out_w, wT2, D_);
    }

    gate_k<<<cg, 256, 0, stream>>>(xs, x, wacc, g);

    gemm_k<false><<<gg, 256, 0, stream>>>(g, wT2, out_b, out, nullptr, nullptr,
                                          MROWS, NDIM, KDIM);
}